// Round 3
// baseline (20210.379 us; speedup 1.0000x reference)
//
#include <hip/hip_runtime.h>
#include <math.h>

// ---------------- constants ----------------
#define Bc   32
#define Nc   379
#define Hc   512
#define NHc  8
#define Pc   3
#define HDc  64          // H/NH
#define NNc  (Nc*Nc)     // 143641
#define CB   8           // batch chunk
#define NCHUNK 4
static const size_t NH_f  = (size_t)Nc*Hc;           // 194,048
static const size_t BNH   = (size_t)Bc*Nc*Hc;        // 6,207,488
#define ROWS_BN   12128   // B*N
#define ROWS_CHUNK 3032   // CB*N
#define ROWS_WG    9096   // CB*P*N
static const size_t CHUNK_NH = (size_t)CB*Nc*Hc;     // 1,552,384
static const size_t PEC_SZ   = (size_t)ROWS_WG*Hc;   // 4,657,152
static const size_t HIDC_SZ  = (size_t)ROWS_CHUNK*4*Hc; // 6,209,536

typedef __attribute__((ext_vector_type(8))) short bf16x8;
typedef __attribute__((ext_vector_type(4))) float f32x4;

__device__ inline float gelu_f(float x) {
    return 0.5f * x * (1.0f + erff(x * 0.7071067811865476f));
}

// fp32 -> bf16 bits, round-to-nearest-even
__device__ inline short f2bf(float f) {
    unsigned u = __float_as_uint(f);
    unsigned r = u + 0x7fffu + ((u >> 16) & 1u);
    return (short)(r >> 16);
}

// block reductions (blockDim == 256)
__device__ inline float blk_sum(float v, float* sh) {
#pragma unroll
    for (int off = 32; off; off >>= 1) v += __shfl_xor(v, off, 64);
    int w = threadIdx.x >> 6;
    __syncthreads();
    if ((threadIdx.x & 63) == 0) sh[w] = v;
    __syncthreads();
    return sh[0] + sh[1] + sh[2] + sh[3];
}
__device__ inline float blk_max(float v, float* sh) {
#pragma unroll
    for (int off = 32; off; off >>= 1) v = fmaxf(v, __shfl_xor(v, off, 64));
    int w = threadIdx.x >> 6;
    __syncthreads();
    if ((threadIdx.x & 63) == 0) sh[w] = v;
    __syncthreads();
    return fmaxf(fmaxf(sh[0], sh[1]), fmaxf(sh[2], sh[3]));
}

// ---------------- bf16 MFMA GEMM ----------------
// C(M,N) = A(M,K)@B(K,N), A,B fp32 in global, converted to bf16 in LDS, fp32 acc.
// Requires N % 128 == 0. M,K arbitrary (guarded / zero-padded).
// Epilogues: 0 none; 1 +bias; 2 gelu(+bias); 3 gelu(+bias + addsrc P-broadcast); 4 *rowscale[row/rs_div]+bias
#define BM 128
#define BN 128
#define BK 32
#define LDK 40   // padded k-stride (bf16 elems); 80 B rows -> 16B-aligned, 2-way-bank-free frag reads

template<int EPI>
__global__ __launch_bounds__(256) void bgemm_k(
    const float* __restrict__ A, const float* __restrict__ B, float* __restrict__ C,
    int M, int N, int K,
    const float* __restrict__ bias,
    const float* __restrict__ rowscale, int rs_div,
    const float* __restrict__ addsrc, int addP, int addN)
{
    __shared__ __attribute__((aligned(16))) short As[BM * LDK];
    __shared__ __attribute__((aligned(16))) short Bs[BN * LDK];
    int tid = threadIdx.x;
    int wave = tid >> 6, lane = tid & 63;
    int wr = wave >> 1, wc = wave & 1;         // 2x2 waves, each 64x64
    int m0 = blockIdx.y * BM, n0 = blockIdx.x * BN;
    int quad = lane >> 4, l16 = lane & 15;
    bool k_vec = ((K & 3) == 0);               // fp32 float4 A loads allowed

    f32x4 acc[4][4] = {};

    for (int k0 = 0; k0 < K; k0 += BK) {
        // ---- stage A tile: 128 x 32, fp32 -> bf16 ----
        {
            int row = tid >> 3;            // 0..31
            int kk  = (tid & 7) * 4;       // 0..28
#pragma unroll
            for (int rr = 0; rr < 4; rr++) {
                int m = row + rr * 32;
                int gm = m0 + m;
                float4 v = make_float4(0.f, 0.f, 0.f, 0.f);
                if (gm < M) {
                    int gk = k0 + kk;
                    const float* src = A + (size_t)gm * K + gk;
                    if (k_vec && gk + 3 < K) v = *(const float4*)src;
                    else {
                        if (gk     < K) v.x = src[0];
                        if (gk + 1 < K) v.y = src[1];
                        if (gk + 2 < K) v.z = src[2];
                        if (gk + 3 < K) v.w = src[3];
                    }
                }
                short* dst = &As[m * LDK + kk];
                dst[0] = f2bf(v.x); dst[1] = f2bf(v.y);
                dst[2] = f2bf(v.z); dst[3] = f2bf(v.w);
            }
        }
        // ---- stage B tile transposed: Bs[n][k], 128 n x 32 k ----
        {
            int kk = tid >> 5;             // 0..7
            int nn = (tid & 31) * 4;       // 0..124
#pragma unroll
            for (int rr = 0; rr < 4; rr++) {
                int k = kk + rr * 8;
                int gk = k0 + k;
                float4 v = make_float4(0.f, 0.f, 0.f, 0.f);
                if (gk < K) v = *(const float4*)(B + (size_t)gk * N + n0 + nn);
                Bs[(nn + 0) * LDK + k] = f2bf(v.x);
                Bs[(nn + 1) * LDK + k] = f2bf(v.y);
                Bs[(nn + 2) * LDK + k] = f2bf(v.z);
                Bs[(nn + 3) * LDK + k] = f2bf(v.w);
            }
        }
        __syncthreads();
        // ---- compute: each wave 4x4 tiles of 16x16, K=32 per mfma ----
        bf16x8 afr[4], bfr[4];
#pragma unroll
        for (int mt = 0; mt < 4; mt++)
            afr[mt] = *(const bf16x8*)&As[(wr * 64 + mt * 16 + l16) * LDK + quad * 8];
#pragma unroll
        for (int nt = 0; nt < 4; nt++)
            bfr[nt] = *(const bf16x8*)&Bs[(wc * 64 + nt * 16 + l16) * LDK + quad * 8];
#pragma unroll
        for (int mt = 0; mt < 4; mt++)
#pragma unroll
            for (int nt = 0; nt < 4; nt++)
                acc[mt][nt] = __builtin_amdgcn_mfma_f32_16x16x32_bf16(
                    afr[mt], bfr[nt], acc[mt][nt], 0, 0, 0);
        __syncthreads();
    }
    // ---- epilogue: C/D layout col=lane&15, row=quad*4+reg ----
#pragma unroll
    for (int mt = 0; mt < 4; mt++) {
#pragma unroll
        for (int nt = 0; nt < 4; nt++) {
#pragma unroll
            for (int r = 0; r < 4; r++) {
                int gm = m0 + wr * 64 + mt * 16 + quad * 4 + r;
                int gn = n0 + wc * 64 + nt * 16 + l16;
                if (gm < M) {
                    float v = acc[mt][nt][r];
                    if (EPI == 1 || EPI == 2 || EPI == 3) v += bias[gn];
                    if (EPI == 4) v = v * rowscale[gm / rs_div] + bias[gn];
                    if (EPI == 3) {
                        int addrow = (gm / (addP * addN)) * addN + (gm % addN);
                        v += addsrc[(size_t)addrow * N + gn];
                    }
                    if (EPI == 2 || EPI == 3) v = gelu_f(v);
                    C[(size_t)gm * N + gn] = v;
                }
            }
        }
    }
}

template<int EPI>
static void launch_bgemm(const float* A, const float* B, float* C, int M, int N, int K,
                         const float* bias, const float* rowscale, int rs_div,
                         const float* addsrc, int addP, int addN, hipStream_t st) {
    dim3 grid(N / 128, (M + 127) / 128);
    bgemm_k<EPI><<<grid, 256, 0, st>>>(A, B, C, M, N, K, bias, rowscale, rs_div, addsrc, addP, addN);
}

// ---------------- LayerNorm (rows of 512) ----------------
__global__ __launch_bounds__(256) void ln_k(const float* __restrict__ x,
                                            const float* __restrict__ g,
                                            const float* __restrict__ b,
                                            float* __restrict__ z) {
    __shared__ float sh[4];
    int r = blockIdx.x, t = threadIdx.x;
    const float* xr = x + (size_t)r * Hc;
    float v0 = xr[t], v1 = xr[t + 256];
    float sum = blk_sum(v0 + v1, sh);
    float sq  = blk_sum(v0 * v0 + v1 * v1, sh);
    float mean = sum * (1.f / Hc);
    float var  = sq * (1.f / Hc) - mean * mean;
    float inv  = rsqrtf(var + 1e-5f);
    float* zr = z + (size_t)r * Hc;
    zr[t]       = (v0 - mean) * inv * g[t]       + b[t];
    zr[t + 256] = (v1 - mean) * inv * g[t + 256] + b[t + 256];
}

// ---------------- weight-gen stats ----------------
__global__ __launch_bounds__(256) void wg_stats_k(const float* __restrict__ pri,
                                                  const float* __restrict__ conn,
                                                  float* __restrict__ mass, float* __restrict__ dot,
                                                  float* __restrict__ nrmp, float* __restrict__ nrmc) {
    __shared__ float sh[4];
    int bp = blockIdx.x;
    int b = bp >> 2, r = bp & 3;   // P+1 == 4
    const float* c = conn + (size_t)b * NNc;
    if (r < Pc) {
        const float* p = pri + (size_t)(b * Pc + r) * NNc;
        float sa = 0, sq = 0, sd = 0;
        for (int i = threadIdx.x; i < NNc; i += blockDim.x) {
            float pv = p[i], cv = c[i];
            sa += fabsf(pv); sq += pv * pv; sd += pv * cv;
        }
        sa = blk_sum(sa, sh);
        sq = blk_sum(sq, sh);
        sd = blk_sum(sd, sh);
        if (threadIdx.x == 0) { mass[b * Pc + r] = sa; nrmp[b * Pc + r] = sqrtf(sq); dot[b * Pc + r] = sd; }
    } else {
        float sq = 0;
        for (int i = threadIdx.x; i < NNc; i += blockDim.x) { float cv = c[i]; sq += cv * cv; }
        sq = blk_sum(sq, sh);
        if (threadIdx.x == 0) nrmc[b] = sqrtf(sq);
    }
}

__global__ void wg_sw_k(const float* mass, const float* dot, const float* nrmp, const float* nrmc,
                        float* sw, float* invm) {
    int b = threadIdx.x;
    if (b >= Bc) return;
    float nc = fmaxf(nrmc[b], 1e-12f);
    float s[Pc];
    for (int p = 0; p < Pc; p++) s[p] = dot[b * Pc + p] / (nc * fmaxf(nrmp[b * Pc + p], 1e-12f));
    float m = fmaxf(s[0], fmaxf(s[1], s[2]));
    float e[Pc], sum = 0;
    for (int p = 0; p < Pc; p++) { e[p] = expf(s[p] - m); sum += e[p]; }
    for (int p = 0; p < Pc; p++) {
        sw[b * Pc + p] = e[p] / sum;
        invm[b * Pc + p] = 1.f / mass[b * Pc + p];
    }
}

__global__ void fused_nh_k(const float* __restrict__ PEc, const float* __restrict__ swp,
                           float* __restrict__ FNp, size_t count) {
    size_t idx = (size_t)blockIdx.x * blockDim.x + threadIdx.x;
    if (idx >= count) return;
    int bl = (int)(idx / NH_f);
    size_t within = idx % NH_f;
    const float* sw = swp + bl * Pc;
    size_t base = (size_t)bl * Pc * NH_f + within;
    FNp[idx] = sw[0] * PEc[base] + sw[1] * PEc[base + NH_f] + sw[2] * PEc[base + 2 * NH_f];
}

__global__ __launch_bounds__(512) void tokens_k(const float* __restrict__ F2, float* __restrict__ TOK) {
    int bp = blockIdx.x, h = threadIdx.x;
    const float* base = F2 + (size_t)bp * NH_f + h;
    float s = 0;
    for (int n = 0; n < Nc; n++) s += base[(size_t)n * Hc];
    TOK[(size_t)bp * Hc + h] = s * (1.0f / (float)Nc);
}

__global__ __launch_bounds__(64) void wg_attn_k(const float* __restrict__ QW,
                                                float* __restrict__ aw_out, float* __restrict__ msum) {
    int b = blockIdx.x, lane = threadIdx.x;
    float s[4][Pc][Pc];
    for (int h = 0; h < 4; h++)
        for (int i = 0; i < Pc; i++)
            for (int j = 0; j < Pc; j++) {
                const float* q = QW + (size_t)(b * Pc + i) * 1536 + h * 128;
                const float* k = QW + (size_t)(b * Pc + j) * 1536 + 512 + h * 128;
                float p = q[lane] * k[lane] + q[lane + 64] * k[lane + 64];
#pragma unroll
                for (int off = 32; off; off >>= 1) p += __shfl_xor(p, off, 64);
                s[h][i][j] = p * 0.08838834764831845f;  // 1/sqrt(128)
            }
    float aw[Pc] = {0, 0, 0};
    for (int h = 0; h < 4; h++)
        for (int i = 0; i < Pc; i++) {
            float m = fmaxf(s[h][i][0], fmaxf(s[h][i][1], s[h][i][2]));
            float e0 = expf(s[h][i][0] - m), e1 = expf(s[h][i][1] - m), e2 = expf(s[h][i][2] - m);
            float inv = 1.f / (e0 + e1 + e2);
            aw[0] += e0 * inv; aw[1] += e1 * inv; aw[2] += e2 * inv;
        }
    for (int j = 0; j < Pc; j++) aw[j] *= (1.f / 12.f);
    float m2 = fmaxf(aw[0], fmaxf(aw[1], aw[2]));
    float e0 = expf((aw[0] - m2) * 100.f), e1 = expf((aw[1] - m2) * 100.f), e2 = expf((aw[2] - m2) * 100.f);
    float inv = 1.f / (e0 + e1 + e2);
    if (lane == 0) {
        aw_out[b * Pc + 0] = e0 * inv;
        aw_out[b * Pc + 1] = e1 * inv;
        aw_out[b * Pc + 2] = e2 * inv;
        msum[b] = (e0 + e1 + e2) * inv;
    }
}

// ---------------- tiled attention: block = (16 queries, head, batch-local) ----------------
#define QT 16
__global__ __launch_bounds__(256) void attn_k(const float* __restrict__ QKVc,
                                              const float* __restrict__ conn,
                                              const float* __restrict__ msum,
                                              const float* __restrict__ alpha,
                                              int b0, float* __restrict__ ctx) {
    __shared__ float Qs[QT][68];
    __shared__ float Ks[64][68];      // reused for V
    __shared__ float Ss[QT][385];
    __shared__ float ssum[QT];
    int i0 = blockIdx.x * QT;
    int h = blockIdx.y, bl = blockIdx.z;
    int b = b0 + bl;
    int t = threadIdx.x;
    int wave = t >> 6, lane = t & 63;
    float a2 = 0.5f * alpha[0];
    float mterm = a2 * msum[b];

    // Q tile: 16 rows x 64 dims (coalesced float4)
    {
        int q = t >> 4, dd = (t & 15) * 4;
        int gi = i0 + q;
        int sr = gi < Nc ? gi : Nc - 1;
        const float* src = QKVc + ((size_t)bl * Nc + sr) * 1536 + h * HDc + dd;
        float4 v = *(const float4*)src;
        if (gi >= Nc) v = make_float4(0.f, 0.f, 0.f, 0.f);
        *(float4*)&Qs[q][dd] = v;
    }
    int q = t >> 4, jl = t & 15;
    // ---- scores ----
    for (int jt = 0; jt < 6; jt++) {
        __syncthreads();
        {   // K tile 64x64
            int j = t >> 2, dd = (t & 3) * 16;
            int gj = jt * 64 + j;
            int sr = gj < Nc ? gj : Nc - 1;
            const float* src = QKVc + ((size_t)bl * Nc + sr) * 1536 + Hc + h * HDc + dd;
            *(float4*)&Ks[j][dd]      = *(const float4*)(src);
            *(float4*)&Ks[j][dd + 4]  = *(const float4*)(src + 4);
            *(float4*)&Ks[j][dd + 8]  = *(const float4*)(src + 8);
            *(float4*)&Ks[j][dd + 12] = *(const float4*)(src + 12);
        }
        __syncthreads();
        float accj[4] = {0.f, 0.f, 0.f, 0.f};
        for (int d = 0; d < HDc; d++) {
            float qv = Qs[q][d];
#pragma unroll
            for (int jj = 0; jj < 4; jj++) accj[jj] += qv * Ks[jl + 16 * jj][d];
        }
        int gi = i0 + q;
        const float* Crow = conn + ((size_t)b * Nc + (gi < Nc ? gi : Nc - 1)) * Nc;
#pragma unroll
        for (int jj = 0; jj < 4; jj++) {
            int gj = jt * 64 + jl + 16 * jj;
            if (gj < Nc) {
                float mk = tanhf(mterm + (1.f - a2) * Crow[gj]);
                Ss[q][gj] = accj[jj] * 0.125f * (1.f + mk);
            }
        }
    }
    __syncthreads();
    // ---- softmax (unnormalized exp; 4 waves x 4 rows) ----
    for (int qi = 0; qi < 4; qi++) {
        int qq = wave * 4 + qi;
        float m = -3.4e38f;
        for (int j = lane; j < Nc; j += 64) m = fmaxf(m, Ss[qq][j]);
#pragma unroll
        for (int off = 32; off; off >>= 1) m = fmaxf(m, __shfl_xor(m, off, 64));
        float sum = 0.f;
        for (int j = lane; j < Nc; j += 64) { float e = expf(Ss[qq][j] - m); Ss[qq][j] = e; sum += e; }
#pragma unroll
        for (int off = 32; off; off >>= 1) sum += __shfl_xor(sum, off, 64);
        if (lane == 0) ssum[qq] = sum;
    }
    // ---- PV ----
    float accv[4] = {0.f, 0.f, 0.f, 0.f};
    int dl = t & 15;
    for (int jt = 0; jt < 6; jt++) {
        __syncthreads();
        {   // V tile 64x64 into Ks
            int j = t >> 2, dd = (t & 3) * 16;
            int gj = jt * 64 + j;
            int sr = gj < Nc ? gj : Nc - 1;
            const float* src = QKVc + ((size_t)bl * Nc + sr) * 1536 + 2 * Hc + h * HDc + dd;
            *(float4*)&Ks[j][dd]      = *(const float4*)(src);
            *(float4*)&Ks[j][dd + 4]  = *(const float4*)(src + 4);
            *(float4*)&Ks[j][dd + 8]  = *(const float4*)(src + 8);
            *(float4*)&Ks[j][dd + 12] = *(const float4*)(src + 12);
        }
        __syncthreads();
        int lim = Nc - jt * 64; if (lim > 64) lim = 64;
        for (int j = 0; j < lim; j++) {
            float p = Ss[q][jt * 64 + j];
#pragma unroll
            for (int d4 = 0; d4 < 4; d4++) accv[d4] += p * Ks[j][dl + 16 * d4];
        }
    }
    int gi = i0 + q;
    if (gi < Nc) {
        float inv = 1.f / ssum[q];
        float* dst = ctx + ((size_t)b * Nc + gi) * Hc + h * HDc;
#pragma unroll
        for (int d4 = 0; d4 < 4; d4++) dst[dl + 16 * d4] = accv[d4] * inv;
    }
}

__global__ void add3_k(const float* __restrict__ x, float* __restrict__ ctx,
                       const float* __restrict__ fn, size_t count) {
    size_t idx = (size_t)blockIdx.x * blockDim.x + threadIdx.x;
    if (idx >= count) return;
    ctx[idx] = x[idx] + ctx[idx] + fn[idx];
}

__global__ void final_k(const float* __restrict__ AO, const float* __restrict__ FF,
                        const float* __restrict__ dw,
                        float* __restrict__ xout, float* __restrict__ proj, size_t count) {
    size_t idx = (size_t)blockIdx.x * blockDim.x + threadIdx.x;
    if (idx >= count) return;
    float w = dw[0];
    float ff = FF[idx];
    float xn = AO[idx] + ff;
    xout[idx] = xn;
    proj[idx] = w * ff + (1.f - w) * xn;
}

__global__ __launch_bounds__(256) void final_kl_k(const float* __restrict__ AO,
                                                  const float* __restrict__ FF,
                                                  const float* __restrict__ dw,
                                                  const float* __restrict__ PF,
                                                  float* __restrict__ xout,
                                                  float* __restrict__ acc) {
    __shared__ float sh[4];
    int r = blockIdx.x, t = threadIdx.x;
    size_t base = (size_t)r * Hc;
    float w = dw[1];
    float ff0 = FF[base + t], ff1 = FF[base + t + 256];
    float ao0 = AO[base + t], ao1 = AO[base + t + 256];
    float xn0 = ao0 + ff0, xn1 = ao1 + ff1;
    xout[base + t] = xn0;
    xout[base + t + 256] = xn1;
    float s0 = w * ff0 + (1.f - w) * xn0;
    float s1 = w * ff1 + (1.f - w) * xn1;
    float f0 = PF[base + t], f1 = PF[base + t + 256];
    float mf = blk_max(fmaxf(f0, f1), sh);
    float ms = blk_max(fmaxf(s0, s1), sh);
    float ef = expf(f0 - mf) + expf(f1 - mf);
    float es = expf(s0 - ms) + expf(s1 - ms);
    float sf = blk_sum(ef, sh);
    float ss = blk_sum(es, sh);
    float lsef = mf + logf(sf), lses = ms + logf(ss);
    float lf0 = f0 - lsef, lf1 = f1 - lsef, ls0 = s0 - lses, ls1 = s1 - lses;
    float tsum = expf(ls0) * (ls0 - lf0) + expf(ls1) * (ls1 - lf1)
               + expf(lf0) * (lf0 - ls0) + expf(lf1) * (lf1 - ls1);
    tsum = blk_sum(tsum, sh);
    if (t == 0) atomicAdd(acc, tsum);
}

__global__ void kl_final_k(const float* __restrict__ acc, float* __restrict__ out) {
    out[0] = 0.5f * acc[0] * (1.0f / (float)ROWS_BN);
}

// ---------------- launch ----------------
extern "C" void kernel_launch(void* const* d_in, const int* in_sizes, int n_in,
                              void* d_out, int out_size, void* d_ws, size_t ws_size,
                              hipStream_t stream) {
    (void)in_sizes; (void)n_in; (void)out_size; (void)ws_size;
    const float* x[2]    = {(const float*)d_in[0], (const float*)d_in[1]};
    const float* pri[2]  = {(const float*)d_in[2], (const float*)d_in[3]};
    const float* conn[2] = {(const float*)d_in[4], (const float*)d_in[5]};
    const float* dw      = (const float*)d_in[6];
    const float* wqkv[2] = {(const float*)d_in[7], (const float*)d_in[8]};
    const float* ln_g    = (const float*)d_in[9];
    const float* ln_b    = (const float*)d_in[10];
    const float* ffn_w1  = (const float*)d_in[11];
    const float* ffn_b1  = (const float*)d_in[12];
    const float* ffn_w2  = (const float*)d_in[13];
    const float* ffn_b2  = (const float*)d_in[14];
    const float* pw      = (const float*)d_in[15];
    const float* pb      = (const float*)d_in[16];
    const float* f1w     = (const float*)d_in[17];
    const float* f1b     = (const float*)d_in[18];
    const float* f2w     = (const float*)d_in[19];
    const float* f2b     = (const float*)d_in[20];
    const float* ipw     = (const float*)d_in[21];
    const float* ipb     = (const float*)d_in[22];
    const float* alpha   = (const float*)d_in[23];
    float* out = (float*)d_out;

    // --- workspace arena (~150 MB) ---
    float* W = (float*)d_ws;
    size_t o = 0;
    auto alloc = [&](size_t n) { float* p = W + o; o += n; return p; };
    float* Z     = alloc(BNH);
    float* CTX   = alloc(BNH);
    float* FN    = alloc(BNH);
    float* PROJ0 = alloc(BNH);
    float* R     = alloc(12417024);          // shared transient region
    float* TOK   = alloc((size_t)96 * Hc);
    float* QKVWG = alloc((size_t)96 * 1536);
    float* MASS  = alloc(96); float* DOT = alloc(96); float* NRMP = alloc(96);
    float* NRMC  = alloc(32); float* SW  = alloc(96); float* INVM = alloc(96);
    float* MSUM  = alloc(32);
    float* KLACC = alloc(1);

    // R overlays (disjoint lifetimes; same-stream ordering serializes):
    float* PEc  = R;                          // 4,657,152
    float* H1c  = R + PEC_SZ;                 // 4,657,152
    float* ZFc  = R + 2 * PEC_SZ;             // 1,552,384
    float* QKVc = R;                          // 4,657,152
    float* HIDc = R;                          // 6,209,536
    float* FFNOUT = R + HIDC_SZ;              // 6,207,488

    const size_t OUT_DISTILL = 2 * BNH;
    const size_t OUT_AW = 2 * BNH + 1;

    hipMemsetAsync(KLACC, 0, sizeof(float), stream);

    int eb = 256;
    int gBNH = (int)((BNH + eb - 1) / eb);
    int gCHK = (int)((CHUNK_NH + eb - 1) / eb);

    for (int s = 0; s < 2; s++) {
        ln_k<<<ROWS_BN, 256, 0, stream>>>(x[s], ln_g + s * Hc, ln_b + s * Hc, Z);
        wg_stats_k<<<Bc * (Pc + 1), 256, 0, stream>>>(pri[s], conn[s], MASS, DOT, NRMP, NRMC);
        wg_sw_k<<<1, 64, 0, stream>>>(MASS, DOT, NRMP, NRMC, SW, INVM);

        // ---- weight-gen pipeline, chunked over batches ----
        for (int c = 0; c < NCHUNK; c++) {
            const float* pric = pri[s] + (size_t)c * ROWS_WG * Nc;
            launch_bgemm<0>(Z + (size_t)c * ROWS_CHUNK * Hc, f1w + (size_t)Hc * Hc, ZFc,
                            ROWS_CHUNK, Hc, Hc, nullptr, nullptr, 0, nullptr, 0, 0, stream);
            launch_bgemm<4>(pric, pw, PEc, ROWS_WG, Hc, Nc, pb, INVM + c * CB * Pc, Nc,
                            nullptr, 0, 0, stream);
            fused_nh_k<<<gCHK, eb, 0, stream>>>(PEc, SW + c * CB * Pc, FN + (size_t)c * CHUNK_NH, CHUNK_NH);
            launch_bgemm<3>(PEc, f1w, H1c, ROWS_WG, Hc, Hc, f1b, nullptr, 0, ZFc, Pc, Nc, stream);
            launch_bgemm<1>(H1c, f2w, PEc, ROWS_WG, Hc, Hc, f2b, nullptr, 0, nullptr, 0, 0, stream);
            tokens_k<<<CB * Pc, 512, 0, stream>>>(PEc, TOK + (size_t)c * CB * Pc * Hc);
        }
        launch_bgemm<1>(TOK, ipw, QKVWG, Bc * Pc, 3 * Hc, Hc, ipb, nullptr, 0, nullptr, 0, 0, stream);
        wg_attn_k<<<Bc, 64, 0, stream>>>(QKVWG, out + OUT_AW + (size_t)s * (Bc * Pc), MSUM);

        // ---- main attention, chunked over batches ----
        for (int c = 0; c < NCHUNK; c++) {
            launch_bgemm<0>(Z + (size_t)c * ROWS_CHUNK * Hc, wqkv[s], QKVc,
                            ROWS_CHUNK, 3 * Hc, Hc, nullptr, nullptr, 0, nullptr, 0, 0, stream);
            attn_k<<<dim3((Nc + QT - 1) / QT, NHc, CB), 256, 0, stream>>>(
                QKVc, conn[s], MSUM, alpha, c * CB, CTX);
        }
        add3_k<<<gBNH, eb, 0, stream>>>(x[s], CTX, FN, BNH);

        // ---- FFN, chunked rows ----
        ln_k<<<ROWS_BN, 256, 0, stream>>>(CTX, ln_g + (2 + s) * Hc, ln_b + (2 + s) * Hc, Z);
        for (int c = 0; c < NCHUNK; c++) {
            launch_bgemm<2>(Z + (size_t)c * ROWS_CHUNK * Hc, ffn_w1 + (size_t)s * Hc * 4 * Hc, HIDc,
                            ROWS_CHUNK, 4 * Hc, Hc, ffn_b1 + (size_t)s * 4 * Hc,
                            nullptr, 0, nullptr, 0, 0, stream);
            launch_bgemm<1>(HIDc, ffn_w2 + (size_t)s * 4 * Hc * Hc, FFNOUT + (size_t)c * ROWS_CHUNK * Hc,
                            ROWS_CHUNK, Hc, 4 * Hc, ffn_b2 + (size_t)s * Hc,
                            nullptr, 0, nullptr, 0, 0, stream);
        }
        if (s == 0) {
            final_k<<<gBNH, eb, 0, stream>>>(CTX, FFNOUT, dw, out, PROJ0, BNH);
        } else {
            final_kl_k<<<ROWS_BN, 256, 0, stream>>>(CTX, FFNOUT, dw, PROJ0, out + BNH, KLACC);
        }
    }
    kl_final_k<<<1, 1, 0, stream>>>(KLACC, out + OUT_DISTILL);
}

// Round 4
// 8130.535 us; speedup vs baseline: 2.4857x; 2.4857x over previous
//
#include <hip/hip_runtime.h>
#include <math.h>

// ---------------- constants ----------------
#define Bc   32
#define Nc   379
#define Hc   512
#define NHc  8
#define Pc   3
#define HDc  64          // H/NH
#define NNc  (Nc*Nc)     // 143641
#define CB   8           // batch chunk
#define NCHUNK 4
static const size_t NH_f  = (size_t)Nc*Hc;           // 194,048
static const size_t BNH   = (size_t)Bc*Nc*Hc;        // 6,207,488
#define ROWS_BN   12128   // B*N
#define ROWS_CHUNK 3032   // CB*N
#define ROWS_WG    9096   // CB*P*N
static const size_t CHUNK_NH = (size_t)CB*Nc*Hc;     // 1,552,384
static const size_t PEC_SZ   = (size_t)ROWS_WG*Hc;   // 4,657,152
static const size_t HIDC_SZ  = (size_t)ROWS_CHUNK*4*Hc; // 6,209,536

typedef __attribute__((ext_vector_type(8))) short bf16x8;
typedef __attribute__((ext_vector_type(4))) float f32x4;

__device__ inline float gelu_f(float x) {
    return 0.5f * x * (1.0f + erff(x * 0.7071067811865476f));
}

// fp32 -> bf16 bits, round-to-nearest-even
__device__ inline short f2bf(float f) {
    unsigned u = __float_as_uint(f);
    unsigned r = u + 0x7fffu + ((u >> 16) & 1u);
    return (short)(r >> 16);
}

// block reductions (blockDim == 256)
__device__ inline float blk_sum(float v, float* sh) {
#pragma unroll
    for (int off = 32; off; off >>= 1) v += __shfl_xor(v, off, 64);
    int w = threadIdx.x >> 6;
    __syncthreads();
    if ((threadIdx.x & 63) == 0) sh[w] = v;
    __syncthreads();
    return sh[0] + sh[1] + sh[2] + sh[3];
}
__device__ inline float blk_max(float v, float* sh) {
#pragma unroll
    for (int off = 32; off; off >>= 1) v = fmaxf(v, __shfl_xor(v, off, 64));
    int w = threadIdx.x >> 6;
    __syncthreads();
    if ((threadIdx.x & 63) == 0) sh[w] = v;
    __syncthreads();
    return fmaxf(fmaxf(sh[0], sh[1]), fmaxf(sh[2], sh[3]));
}

// ---------------- bf16 MFMA GEMM ----------------
// C(M,N) = A(M,K)@B(K,N), A,B fp32 in global, converted to bf16 in LDS, fp32 acc.
// Requires N % 128 == 0. M,K arbitrary (guarded / zero-padded).
// Epilogues: 0 none; 1 +bias; 2 gelu(+bias); 3 gelu(+bias + addsrc P-broadcast); 4 *rowscale[row/rs_div]+bias
#define BM 128
#define BN 128
#define BK 32
#define LDK 40   // padded k-stride (bf16 elems)

template<int EPI>
__global__ __launch_bounds__(256) void bgemm_k(
    const float* __restrict__ A, const float* __restrict__ B, float* __restrict__ C,
    int M, int N, int K,
    const float* __restrict__ bias,
    const float* __restrict__ rowscale, int rs_div,
    const float* __restrict__ addsrc, int addP, int addN)
{
    __shared__ __attribute__((aligned(16))) short As[BM * LDK];
    __shared__ __attribute__((aligned(16))) short Bs[BN * LDK];
    int tid = threadIdx.x;
    int wave = tid >> 6, lane = tid & 63;
    int wr = wave >> 1, wc = wave & 1;         // 2x2 waves, each 64x64
    int m0 = blockIdx.y * BM, n0 = blockIdx.x * BN;
    int quad = lane >> 4, l16 = lane & 15;
    bool k_vec = ((K & 3) == 0);

    f32x4 acc[4][4] = {};

    for (int k0 = 0; k0 < K; k0 += BK) {
        // ---- stage A tile: 128 x 32, fp32 -> bf16 ----
        {
            int row = tid >> 3;            // 0..31
            int kk  = (tid & 7) * 4;       // 0..28
#pragma unroll
            for (int rr = 0; rr < 4; rr++) {
                int m = row + rr * 32;
                int gm = m0 + m;
                float4 v = make_float4(0.f, 0.f, 0.f, 0.f);
                if (gm < M) {
                    int gk = k0 + kk;
                    const float* src = A + (size_t)gm * K + gk;
                    if (k_vec && gk + 3 < K) v = *(const float4*)src;
                    else {
                        if (gk     < K) v.x = src[0];
                        if (gk + 1 < K) v.y = src[1];
                        if (gk + 2 < K) v.z = src[2];
                        if (gk + 3 < K) v.w = src[3];
                    }
                }
                short* dst = &As[m * LDK + kk];
                dst[0] = f2bf(v.x); dst[1] = f2bf(v.y);
                dst[2] = f2bf(v.z); dst[3] = f2bf(v.w);
            }
        }
        // ---- stage B tile transposed: Bs[n][k], 128 n x 32 k ----
        {
            int kk = tid >> 5;             // 0..7
            int nn = (tid & 31) * 4;       // 0..124
#pragma unroll
            for (int rr = 0; rr < 4; rr++) {
                int k = kk + rr * 8;
                int gk = k0 + k;
                float4 v = make_float4(0.f, 0.f, 0.f, 0.f);
                if (gk < K) v = *(const float4*)(B + (size_t)gk * N + n0 + nn);
                Bs[(nn + 0) * LDK + k] = f2bf(v.x);
                Bs[(nn + 1) * LDK + k] = f2bf(v.y);
                Bs[(nn + 2) * LDK + k] = f2bf(v.z);
                Bs[(nn + 3) * LDK + k] = f2bf(v.w);
            }
        }
        __syncthreads();
        bf16x8 afr[4], bfr[4];
#pragma unroll
        for (int mt = 0; mt < 4; mt++)
            afr[mt] = *(const bf16x8*)&As[(wr * 64 + mt * 16 + l16) * LDK + quad * 8];
#pragma unroll
        for (int nt = 0; nt < 4; nt++)
            bfr[nt] = *(const bf16x8*)&Bs[(wc * 64 + nt * 16 + l16) * LDK + quad * 8];
#pragma unroll
        for (int mt = 0; mt < 4; mt++)
#pragma unroll
            for (int nt = 0; nt < 4; nt++)
                acc[mt][nt] = __builtin_amdgcn_mfma_f32_16x16x32_bf16(
                    afr[mt], bfr[nt], acc[mt][nt], 0, 0, 0);
        __syncthreads();
    }
    // ---- epilogue: C/D layout col=lane&15, row=quad*4+reg ----
#pragma unroll
    for (int mt = 0; mt < 4; mt++) {
#pragma unroll
        for (int nt = 0; nt < 4; nt++) {
#pragma unroll
            for (int r = 0; r < 4; r++) {
                int gm = m0 + wr * 64 + mt * 16 + quad * 4 + r;
                int gn = n0 + wc * 64 + nt * 16 + l16;
                if (gm < M) {
                    float v = acc[mt][nt][r];
                    if (EPI == 1 || EPI == 2 || EPI == 3) v += bias[gn];
                    if (EPI == 4) v = v * rowscale[gm / rs_div] + bias[gn];
                    if (EPI == 3) {
                        int addrow = (gm / (addP * addN)) * addN + (gm % addN);
                        v += addsrc[(size_t)addrow * N + gn];
                    }
                    if (EPI == 2 || EPI == 3) v = gelu_f(v);
                    C[(size_t)gm * N + gn] = v;
                }
            }
        }
    }
}

template<int EPI>
static void launch_bgemm(const float* A, const float* B, float* C, int M, int N, int K,
                         const float* bias, const float* rowscale, int rs_div,
                         const float* addsrc, int addP, int addN, hipStream_t st) {
    dim3 grid(N / 128, (M + 127) / 128);
    bgemm_k<EPI><<<grid, 256, 0, st>>>(A, B, C, M, N, K, bias, rowscale, rs_div, addsrc, addP, addN);
}

// ---------------- LayerNorm (rows of 512) ----------------
__global__ __launch_bounds__(256) void ln_k(const float* __restrict__ x,
                                            const float* __restrict__ g,
                                            const float* __restrict__ b,
                                            float* __restrict__ z) {
    __shared__ float sh[4];
    int r = blockIdx.x, t = threadIdx.x;
    const float* xr = x + (size_t)r * Hc;
    float v0 = xr[t], v1 = xr[t + 256];
    float sum = blk_sum(v0 + v1, sh);
    float sq  = blk_sum(v0 * v0 + v1 * v1, sh);
    float mean = sum * (1.f / Hc);
    float var  = sq * (1.f / Hc) - mean * mean;
    float inv  = rsqrtf(var + 1e-5f);
    float* zr = z + (size_t)r * Hc;
    zr[t]       = (v0 - mean) * inv * g[t]       + b[t];
    zr[t + 256] = (v1 - mean) * inv * g[t + 256] + b[t + 256];
}

// ---------------- weight-gen stats ----------------
__global__ __launch_bounds__(256) void wg_stats_k(const float* __restrict__ pri,
                                                  const float* __restrict__ conn,
                                                  float* __restrict__ mass, float* __restrict__ dot,
                                                  float* __restrict__ nrmp, float* __restrict__ nrmc) {
    __shared__ float sh[4];
    int bp = blockIdx.x;
    int b = bp >> 2, r = bp & 3;   // P+1 == 4
    const float* c = conn + (size_t)b * NNc;
    if (r < Pc) {
        const float* p = pri + (size_t)(b * Pc + r) * NNc;
        float sa = 0, sq = 0, sd = 0;
        for (int i = threadIdx.x; i < NNc; i += blockDim.x) {
            float pv = p[i], cv = c[i];
            sa += fabsf(pv); sq += pv * pv; sd += pv * cv;
        }
        sa = blk_sum(sa, sh);
        sq = blk_sum(sq, sh);
        sd = blk_sum(sd, sh);
        if (threadIdx.x == 0) { mass[b * Pc + r] = sa; nrmp[b * Pc + r] = sqrtf(sq); dot[b * Pc + r] = sd; }
    } else {
        float sq = 0;
        for (int i = threadIdx.x; i < NNc; i += blockDim.x) { float cv = c[i]; sq += cv * cv; }
        sq = blk_sum(sq, sh);
        if (threadIdx.x == 0) nrmc[b] = sqrtf(sq);
    }
}

__global__ void wg_sw_k(const float* mass, const float* dot, const float* nrmp, const float* nrmc,
                        float* sw, float* invm) {
    int b = threadIdx.x;
    if (b >= Bc) return;
    float nc = fmaxf(nrmc[b], 1e-12f);
    float s[Pc];
    for (int p = 0; p < Pc; p++) s[p] = dot[b * Pc + p] / (nc * fmaxf(nrmp[b * Pc + p], 1e-12f));
    float m = fmaxf(s[0], fmaxf(s[1], s[2]));
    float e[Pc], sum = 0;
    for (int p = 0; p < Pc; p++) { e[p] = expf(s[p] - m); sum += e[p]; }
    for (int p = 0; p < Pc; p++) {
        sw[b * Pc + p] = e[p] / sum;
        invm[b * Pc + p] = 1.f / mass[b * Pc + p];
    }
}

__global__ void fused_nh_k(const float* __restrict__ PEc, const float* __restrict__ swp,
                           float* __restrict__ FNp, size_t count) {
    size_t idx = (size_t)blockIdx.x * blockDim.x + threadIdx.x;
    if (idx >= count) return;
    int bl = (int)(idx / NH_f);
    size_t within = idx % NH_f;
    const float* sw = swp + bl * Pc;
    size_t base = (size_t)bl * Pc * NH_f + within;
    FNp[idx] = sw[0] * PEc[base] + sw[1] * PEc[base + NH_f] + sw[2] * PEc[base + 2 * NH_f];
}

__global__ __launch_bounds__(512) void tokens_k(const float* __restrict__ F2, float* __restrict__ TOK) {
    int bp = blockIdx.x, h = threadIdx.x;
    const float* base = F2 + (size_t)bp * NH_f + h;
    float s = 0;
    for (int n = 0; n < Nc; n++) s += base[(size_t)n * Hc];
    TOK[(size_t)bp * Hc + h] = s * (1.0f / (float)Nc);
}

__global__ __launch_bounds__(64) void wg_attn_k(const float* __restrict__ QW,
                                                float* __restrict__ aw_out, float* __restrict__ msum) {
    int b = blockIdx.x, lane = threadIdx.x;
    float s[4][Pc][Pc];
    for (int h = 0; h < 4; h++)
        for (int i = 0; i < Pc; i++)
            for (int j = 0; j < Pc; j++) {
                const float* q = QW + (size_t)(b * Pc + i) * 1536 + h * 128;
                const float* k = QW + (size_t)(b * Pc + j) * 1536 + 512 + h * 128;
                float p = q[lane] * k[lane] + q[lane + 64] * k[lane + 64];
#pragma unroll
                for (int off = 32; off; off >>= 1) p += __shfl_xor(p, off, 64);
                s[h][i][j] = p * 0.08838834764831845f;  // 1/sqrt(128)
            }
    float aw[Pc] = {0, 0, 0};
    for (int h = 0; h < 4; h++)
        for (int i = 0; i < Pc; i++) {
            float m = fmaxf(s[h][i][0], fmaxf(s[h][i][1], s[h][i][2]));
            float e0 = expf(s[h][i][0] - m), e1 = expf(s[h][i][1] - m), e2 = expf(s[h][i][2] - m);
            float inv = 1.f / (e0 + e1 + e2);
            aw[0] += e0 * inv; aw[1] += e1 * inv; aw[2] += e2 * inv;
        }
    for (int j = 0; j < Pc; j++) aw[j] *= (1.f / 12.f);
    float m2 = fmaxf(aw[0], fmaxf(aw[1], aw[2]));
    float e0 = expf((aw[0] - m2) * 100.f), e1 = expf((aw[1] - m2) * 100.f), e2 = expf((aw[2] - m2) * 100.f);
    float inv = 1.f / (e0 + e1 + e2);
    if (lane == 0) {
        aw_out[b * Pc + 0] = e0 * inv;
        aw_out[b * Pc + 1] = e1 * inv;
        aw_out[b * Pc + 2] = e2 * inv;
        msum[b] = (e0 + e1 + e2) * inv;
    }
}

// ---------------- flash attention: block = (32 queries, head, batch-local) ----------------
// thread t: q = t>>3 (0..31), sub = t&7. Per-thread state: acc[8] (d-slice sub*8..+7), m, l.
// K/V staged per 64-j tile; exp weights round-trip through Es. ld=66 keeps all LDS reads <=2-way.
#define AQT 32
__global__ __launch_bounds__(256) void fattn_k(const float* __restrict__ QKVc,
                                               const float* __restrict__ conn,
                                               const float* __restrict__ msum,
                                               const float* __restrict__ alpha,
                                               int b0, float* __restrict__ ctx) {
    __shared__ float Qs[AQT][66];
    __shared__ float Ks[64][66];
    __shared__ float Vs[64][66];
    __shared__ float Es[AQT][66];
    int i0 = blockIdx.x * AQT;
    int h = blockIdx.y, bl = blockIdx.z;
    int b = b0 + bl;
    int t = threadIdx.x;
    int q = t >> 3, sub = t & 7;
    int gi = i0 + q;
    float a2 = 0.5f * alpha[0];
    float mterm = a2 * msum[b];
    // stage Q tile (replicate last row for OOB; outputs guarded)
    {
        int src_row = (gi < Nc) ? gi : (Nc - 1);
        int d0 = sub * 8;
        const float* src = QKVc + ((size_t)bl * Nc + src_row) * 1536 + h * HDc + d0;
        *(float4*)&Qs[q][d0]     = *(const float4*)src;
        *(float4*)&Qs[q][d0 + 4] = *(const float4*)(src + 4);
    }
    const float* Crow = conn + ((size_t)b * Nc + (gi < Nc ? gi : Nc - 1)) * Nc;
    float m_run = -3.4e38f, l_run = 0.f;
    float acc[8] = {0.f, 0.f, 0.f, 0.f, 0.f, 0.f, 0.f, 0.f};

    for (int jt = 0; jt < 6; jt++) {
        __syncthreads();   // protect LDS reuse across iterations (also covers Q staging, iter 0)
        {   // stage K + V tiles 64x64
            int j = t >> 2, d0 = (t & 3) * 16;
            int gj = jt * 64 + j;
            int sr = (gj < Nc) ? gj : (Nc - 1);
            const float* kp = QKVc + ((size_t)bl * Nc + sr) * 1536 + Hc + h * HDc + d0;
            const float* vp = kp + Hc;
            *(float4*)&Ks[j][d0]      = *(const float4*)(kp);
            *(float4*)&Ks[j][d0 + 4]  = *(const float4*)(kp + 4);
            *(float4*)&Ks[j][d0 + 8]  = *(const float4*)(kp + 8);
            *(float4*)&Ks[j][d0 + 12] = *(const float4*)(kp + 12);
            *(float4*)&Vs[j][d0]      = *(const float4*)(vp);
            *(float4*)&Vs[j][d0 + 4]  = *(const float4*)(vp + 4);
            *(float4*)&Vs[j][d0 + 8]  = *(const float4*)(vp + 8);
            *(float4*)&Vs[j][d0 + 12] = *(const float4*)(vp + 12);
        }
        __syncthreads();
        // scores: 8 j's per thread (j = sub + 8*jj)
        float s[8] = {0.f, 0.f, 0.f, 0.f, 0.f, 0.f, 0.f, 0.f};
#pragma unroll 4
        for (int d4 = 0; d4 < 16; d4++) {
            float4 qv = *(float4*)&Qs[q][d4 * 4];
#pragma unroll
            for (int jj = 0; jj < 8; jj++) {
                float4 kv = *(float4*)&Ks[sub + 8 * jj][d4 * 4];
                s[jj] += qv.x * kv.x + qv.y * kv.y + qv.z * kv.z + qv.w * kv.w;
            }
        }
        float tile_max = -3.4e38f;
#pragma unroll
        for (int jj = 0; jj < 8; jj++) {
            int gj = jt * 64 + sub + 8 * jj;
            if (gj < Nc && gi < Nc) {
                float mk = tanhf(mterm + (1.f - a2) * Crow[gj]);
                s[jj] = s[jj] * 0.125f * (1.f + mk);
            } else s[jj] = -3.4e38f;
            tile_max = fmaxf(tile_max, s[jj]);
        }
#pragma unroll
        for (int off = 1; off < 8; off <<= 1)
            tile_max = fmaxf(tile_max, __shfl_xor(tile_max, off, 64));
        float m_new = fmaxf(m_run, tile_max);
        float esum = 0.f;
#pragma unroll
        for (int jj = 0; jj < 8; jj++) {
            float e = __expf(s[jj] - m_new);
            Es[q][sub + 8 * jj] = e;
            esum += e;
        }
#pragma unroll
        for (int off = 1; off < 8; off <<= 1)
            esum += __shfl_xor(esum, off, 64);
        float scl = __expf(m_run - m_new);
        l_run = l_run * scl + esum;
        m_run = m_new;
        __syncthreads();  // Es visible
        // PV: thread d-slice d0 = sub*8
#pragma unroll
        for (int dd = 0; dd < 8; dd++) acc[dd] *= scl;
        int d0 = sub * 8;
#pragma unroll 4
        for (int j4 = 0; j4 < 16; j4++) {
            float4 ev = *(float4*)&Es[q][j4 * 4];
#pragma unroll
            for (int u = 0; u < 4; u++) {
                float e = (u == 0) ? ev.x : (u == 1) ? ev.y : (u == 2) ? ev.z : ev.w;
                float4 v0 = *(float4*)&Vs[j4 * 4 + u][d0];
                float4 v1 = *(float4*)&Vs[j4 * 4 + u][d0 + 4];
                acc[0] += e * v0.x; acc[1] += e * v0.y; acc[2] += e * v0.z; acc[3] += e * v0.w;
                acc[4] += e * v1.x; acc[5] += e * v1.y; acc[6] += e * v1.z; acc[7] += e * v1.w;
            }
        }
    }
    if (gi < Nc) {
        float inv = 1.f / l_run;
        float* dst = ctx + ((size_t)b * Nc + gi) * Hc + h * HDc + sub * 8;
        float4 o0 = make_float4(acc[0] * inv, acc[1] * inv, acc[2] * inv, acc[3] * inv);
        float4 o1 = make_float4(acc[4] * inv, acc[5] * inv, acc[6] * inv, acc[7] * inv);
        *(float4*)dst = o0;
        *(float4*)(dst + 4) = o1;
    }
}

__global__ void add3_k(const float* __restrict__ x, float* __restrict__ ctx,
                       const float* __restrict__ fn, size_t count) {
    size_t idx = (size_t)blockIdx.x * blockDim.x + threadIdx.x;
    if (idx >= count) return;
    ctx[idx] = x[idx] + ctx[idx] + fn[idx];
}

__global__ void final_k(const float* __restrict__ AO, const float* __restrict__ FF,
                        const float* __restrict__ dw,
                        float* __restrict__ xout, float* __restrict__ proj, size_t count) {
    size_t idx = (size_t)blockIdx.x * blockDim.x + threadIdx.x;
    if (idx >= count) return;
    float w = dw[0];
    float ff = FF[idx];
    float xn = AO[idx] + ff;
    xout[idx] = xn;
    proj[idx] = w * ff + (1.f - w) * xn;
}

__global__ __launch_bounds__(256) void final_kl_k(const float* __restrict__ AO,
                                                  const float* __restrict__ FF,
                                                  const float* __restrict__ dw,
                                                  const float* __restrict__ PF,
                                                  float* __restrict__ xout,
                                                  float* __restrict__ acc) {
    __shared__ float sh[4];
    int r = blockIdx.x, t = threadIdx.x;
    size_t base = (size_t)r * Hc;
    float w = dw[1];
    float ff0 = FF[base + t], ff1 = FF[base + t + 256];
    float ao0 = AO[base + t], ao1 = AO[base + t + 256];
    float xn0 = ao0 + ff0, xn1 = ao1 + ff1;
    xout[base + t] = xn0;
    xout[base + t + 256] = xn1;
    float s0 = w * ff0 + (1.f - w) * xn0;
    float s1 = w * ff1 + (1.f - w) * xn1;
    float f0 = PF[base + t], f1 = PF[base + t + 256];
    float mf = blk_max(fmaxf(f0, f1), sh);
    float ms = blk_max(fmaxf(s0, s1), sh);
    float ef = expf(f0 - mf) + expf(f1 - mf);
    float es = expf(s0 - ms) + expf(s1 - ms);
    float sf = blk_sum(ef, sh);
    float ss = blk_sum(es, sh);
    float lsef = mf + logf(sf), lses = ms + logf(ss);
    float lf0 = f0 - lsef, lf1 = f1 - lsef, ls0 = s0 - lses, ls1 = s1 - lses;
    float tsum = expf(ls0) * (ls0 - lf0) + expf(ls1) * (ls1 - lf1)
               + expf(lf0) * (lf0 - ls0) + expf(lf1) * (lf1 - ls1);
    tsum = blk_sum(tsum, sh);
    if (t == 0) atomicAdd(acc, tsum);
}

__global__ void kl_final_k(const float* __restrict__ acc, float* __restrict__ out) {
    out[0] = 0.5f * acc[0] * (1.0f / (float)ROWS_BN);
}

// ---------------- launch ----------------
extern "C" void kernel_launch(void* const* d_in, const int* in_sizes, int n_in,
                              void* d_out, int out_size, void* d_ws, size_t ws_size,
                              hipStream_t stream) {
    (void)in_sizes; (void)n_in; (void)out_size; (void)ws_size;
    const float* x[2]    = {(const float*)d_in[0], (const float*)d_in[1]};
    const float* pri[2]  = {(const float*)d_in[2], (const float*)d_in[3]};
    const float* conn[2] = {(const float*)d_in[4], (const float*)d_in[5]};
    const float* dw      = (const float*)d_in[6];
    const float* wqkv[2] = {(const float*)d_in[7], (const float*)d_in[8]};
    const float* ln_g    = (const float*)d_in[9];
    const float* ln_b    = (const float*)d_in[10];
    const float* ffn_w1  = (const float*)d_in[11];
    const float* ffn_b1  = (const float*)d_in[12];
    const float* ffn_w2  = (const float*)d_in[13];
    const float* ffn_b2  = (const float*)d_in[14];
    const float* pw      = (const float*)d_in[15];
    const float* pb      = (const float*)d_in[16];
    const float* f1w     = (const float*)d_in[17];
    const float* f1b     = (const float*)d_in[18];
    const float* f2w     = (const float*)d_in[19];
    const float* f2b     = (const float*)d_in[20];
    const float* ipw     = (const float*)d_in[21];
    const float* ipb     = (const float*)d_in[22];
    const float* alpha   = (const float*)d_in[23];
    float* out = (float*)d_out;

    // --- workspace arena (~150 MB) ---
    float* W = (float*)d_ws;
    size_t o = 0;
    auto alloc = [&](size_t n) { float* p = W + o; o += n; return p; };
    float* Z     = alloc(BNH);
    float* CTX   = alloc(BNH);
    float* FN    = alloc(BNH);
    float* PROJ0 = alloc(BNH);
    float* R     = alloc(12417024);          // shared transient region
    float* TOK   = alloc((size_t)96 * Hc);
    float* QKVWG = alloc((size_t)96 * 1536);
    float* MASS  = alloc(96); float* DOT = alloc(96); float* NRMP = alloc(96);
    float* NRMC  = alloc(32); float* SW  = alloc(96); float* INVM = alloc(96);
    float* MSUM  = alloc(32);
    float* KLACC = alloc(1);

    // R overlays (disjoint lifetimes; same-stream ordering serializes):
    float* PEc  = R;                          // 4,657,152
    float* H1c  = R + PEC_SZ;                 // 4,657,152
    float* ZFc  = R + 2 * PEC_SZ;             // 1,552,384
    float* QKVc = R;                          // 4,657,152
    float* HIDc = R;                          // 6,209,536
    float* FFNOUT = R + HIDC_SZ;              // 6,207,488

    const size_t OUT_DISTILL = 2 * BNH;
    const size_t OUT_AW = 2 * BNH + 1;

    hipMemsetAsync(KLACC, 0, sizeof(float), stream);

    int eb = 256;
    int gBNH = (int)((BNH + eb - 1) / eb);
    int gCHK = (int)((CHUNK_NH + eb - 1) / eb);

    for (int s = 0; s < 2; s++) {
        ln_k<<<ROWS_BN, 256, 0, stream>>>(x[s], ln_g + s * Hc, ln_b + s * Hc, Z);
        wg_stats_k<<<Bc * (Pc + 1), 256, 0, stream>>>(pri[s], conn[s], MASS, DOT, NRMP, NRMC);
        wg_sw_k<<<1, 64, 0, stream>>>(MASS, DOT, NRMP, NRMC, SW, INVM);

        // ---- weight-gen pipeline, chunked over batches ----
        for (int c = 0; c < NCHUNK; c++) {
            const float* pric = pri[s] + (size_t)c * ROWS_WG * Nc;
            launch_bgemm<0>(Z + (size_t)c * ROWS_CHUNK * Hc, f1w + (size_t)Hc * Hc, ZFc,
                            ROWS_CHUNK, Hc, Hc, nullptr, nullptr, 0, nullptr, 0, 0, stream);
            launch_bgemm<4>(pric, pw, PEc, ROWS_WG, Hc, Nc, pb, INVM + c * CB * Pc, Nc,
                            nullptr, 0, 0, stream);
            fused_nh_k<<<gCHK, eb, 0, stream>>>(PEc, SW + c * CB * Pc, FN + (size_t)c * CHUNK_NH, CHUNK_NH);
            launch_bgemm<3>(PEc, f1w, H1c, ROWS_WG, Hc, Hc, f1b, nullptr, 0, ZFc, Pc, Nc, stream);
            launch_bgemm<1>(H1c, f2w, PEc, ROWS_WG, Hc, Hc, f2b, nullptr, 0, nullptr, 0, 0, stream);
            tokens_k<<<CB * Pc, 512, 0, stream>>>(PEc, TOK + (size_t)c * CB * Pc * Hc);
        }
        launch_bgemm<1>(TOK, ipw, QKVWG, Bc * Pc, 3 * Hc, Hc, ipb, nullptr, 0, nullptr, 0, 0, stream);
        wg_attn_k<<<Bc, 64, 0, stream>>>(QKVWG, out + OUT_AW + (size_t)s * (Bc * Pc), MSUM);

        // ---- main attention, chunked over batches ----
        for (int c = 0; c < NCHUNK; c++) {
            launch_bgemm<0>(Z + (size_t)c * ROWS_CHUNK * Hc, wqkv[s], QKVc,
                            ROWS_CHUNK, 3 * Hc, Hc, nullptr, nullptr, 0, nullptr, 0, 0, stream);
            fattn_k<<<dim3((Nc + AQT - 1) / AQT, NHc, CB), 256, 0, stream>>>(
                QKVc, conn[s], MSUM, alpha, c * CB, CTX);
        }
        add3_k<<<gBNH, eb, 0, stream>>>(x[s], CTX, FN, BNH);

        // ---- FFN, chunked rows ----
        ln_k<<<ROWS_BN, 256, 0, stream>>>(CTX, ln_g + (2 + s) * Hc, ln_b + (2 + s) * Hc, Z);
        for (int c = 0; c < NCHUNK; c++) {
            launch_bgemm<2>(Z + (size_t)c * ROWS_CHUNK * Hc, ffn_w1 + (size_t)s * Hc * 4 * Hc, HIDc,
                            ROWS_CHUNK, 4 * Hc, Hc, ffn_b1 + (size_t)s * 4 * Hc,
                            nullptr, 0, nullptr, 0, 0, stream);
            launch_bgemm<1>(HIDc, ffn_w2 + (size_t)s * 4 * Hc * Hc, FFNOUT + (size_t)c * ROWS_CHUNK * Hc,
                            ROWS_CHUNK, Hc, 4 * Hc, ffn_b2 + (size_t)s * Hc,
                            nullptr, 0, nullptr, 0, 0, stream);
        }
        if (s == 0) {
            final_k<<<gBNH, eb, 0, stream>>>(CTX, FFNOUT, dw, out, PROJ0, BNH);
        } else {
            final_kl_k<<<ROWS_BN, 256, 0, stream>>>(CTX, FFNOUT, dw, PROJ0, out + BNH, KLACC);
        }
    }
    kl_final_k<<<1, 1, 0, stream>>>(KLACC, out + OUT_DISTILL);
}